// Round 1
// baseline (336.383 us; speedup 1.0000x reference)
//
#include <hip/hip_runtime.h>
#include <math.h>

#define NN 1600      // H*W
#define BB 8         // batch
#define CC 64        // channels
#define KK 10        // top-k
#define ROWS (BB*NN) // 12800

// ---------------------------------------------------------------------------
// Kernel 1: pre[b,n] = relu( sum_c x[b,c,n]*w_con1[c] + b_con1 )
// ---------------------------------------------------------------------------
__global__ void conv_relu_kernel(const float* __restrict__ x, const float* __restrict__ w,
                                 const float* __restrict__ bsc, float* __restrict__ pre) {
    int gid = blockIdx.x * 256 + threadIdx.x;
    if (gid >= ROWS) return;
    int b = gid / NN, n = gid % NN;
    const float* xb = x + (size_t)b * CC * NN;
    float acc = bsc[0];
#pragma unroll 16
    for (int c = 0; c < CC; ++c) acc = fmaf(xb[(size_t)c * NN + n], w[c], acc);
    pre[gid] = fmaxf(acc, 0.f);
}

// ---------------------------------------------------------------------------
// Kernel 2: xx[b,:] = softmax(pre[b,:]) over the 1600 spatial positions
// One block per batch.
// ---------------------------------------------------------------------------
__global__ void softmax_kernel(const float* __restrict__ pre, float* __restrict__ xx) {
    __shared__ float xs[NN];
    __shared__ float red[256];
    int b = blockIdx.x, tid = threadIdx.x;
    for (int n = tid; n < NN; n += 256) xs[n] = pre[b * NN + n];
    __syncthreads();
    float m = -1e30f;
    for (int n = tid; n < NN; n += 256) m = fmaxf(m, xs[n]);
    red[tid] = m; __syncthreads();
    for (int s = 128; s > 0; s >>= 1) { if (tid < s) red[tid] = fmaxf(red[tid], red[tid + s]); __syncthreads(); }
    float mx = red[0]; __syncthreads();
    float ls = 0.f;
    for (int n = tid; n < NN; n += 256) { float e = expf(xs[n] - mx); xs[n] = e; ls += e; }
    red[tid] = ls; __syncthreads();
    for (int s = 128; s > 0; s >>= 1) { if (tid < s) red[tid] += red[tid + s]; __syncthreads(); }
    float S = red[0];
    for (int n = tid; n < NN; n += 256) xx[b * NN + n] = xs[n] / S;
}

// ---------------------------------------------------------------------------
// Kernel 3: per row i, find the 10 smallest (|xx_i - xx_j|, j) lexicographic
// == first 10 of a stable ascending argsort (matches jnp.argsort ties).
// Then center-replacement: if i not among them, slot 9 := i.
// One wave per row, 4 rows (same batch) per 256-thread block.
// Also accumulates vertex degree DV via int atomics.
// ---------------------------------------------------------------------------
__global__ void __launch_bounds__(256) topk_kernel(const float* __restrict__ xx,
                                                   int* __restrict__ topk, int* __restrict__ DV) {
    __shared__ float xs[NN];
    int tid = threadIdx.x;
    int wid = tid >> 6, lane = tid & 63;
    int row = blockIdx.x * 4 + wid;     // 0..12799, all 4 rows share one batch
    int b = row / NN, i = row % NN;
    for (int t = tid; t < NN; t += 256) xs[t] = xx[b * NN + t];
    __syncthreads();
    float xi = xs[i];
    unsigned long long key[25];
#pragma unroll
    for (int s = 0; s < 25; ++s) {
        int j = lane + 64 * s;
        float d = fabsf(xi - xs[j]);
        key[s] = ((unsigned long long)__float_as_uint(d) << 32) | (unsigned)j;
    }
    bool in_top = false;
    unsigned long long prev = 0;
    int last_idx = 0;
#pragma unroll
    for (int r = 0; r < KK; ++r) {
        unsigned long long best = ~0ull;
#pragma unroll
        for (int s = 0; s < 25; ++s) {
            unsigned long long kv = key[s];
            if ((r == 0 || kv > prev) && kv < best) best = kv;
        }
        for (int off = 32; off > 0; off >>= 1) {
            unsigned long long o = __shfl_xor(best, off);
            best = (o < best) ? o : best;
        }
        prev = best;
        int j = (int)(best & 0xffffffffu);
        in_top = in_top || (j == i);
        if (r < KK - 1) {
            if (lane == 0) {
                topk[row * KK + r] = j;
                atomicAdd(&DV[b * NN + j], 1);
            }
        } else {
            last_idx = j;
        }
    }
    int fin = in_top ? last_idx : i;
    if (lane == 0) {
        topk[row * KK + KK - 1] = fin;
        atomicAdd(&DV[b * NN + fin], 1);
    }
}

// ---------------------------------------------------------------------------
// Kernel 4: dv2 = DV^(-1/2)
// ---------------------------------------------------------------------------
__global__ void dv2_kernel(const int* __restrict__ DV, float* __restrict__ dv2) {
    int i = blockIdx.x * 256 + threadIdx.x;
    if (i < ROWS) dv2[i] = 1.0f / sqrtf((float)DV[i]);
}

// ---------------------------------------------------------------------------
// Kernel 5: P[row,c] = 0.1 * dv2[row] * ( in_row @ W + bias )[c]
// transform=1: in_row[c] := relu(dv2[row] * in[row,c])   (previous layer output)
// One wave per row (lane = output channel), W staged in LDS.
// ---------------------------------------------------------------------------
__global__ void __launch_bounds__(256) lin_kernel(const float* __restrict__ in,
                                                  const float* __restrict__ W,
                                                  const float* __restrict__ bias,
                                                  const float* __restrict__ dv2,
                                                  float* __restrict__ outP, int transform) {
    __shared__ float Wl[CC * CC];
    __shared__ float bl[CC];
    int tid = threadIdx.x;
    for (int t = tid; t < CC * CC; t += 256) Wl[t] = W[t];
    if (tid < CC) bl[tid] = bias[tid];
    __syncthreads();
    int lane = tid & 63, wid = tid >> 6;
    int gw = blockIdx.x * 4 + wid;
    int nw = gridDim.x * 4;
    for (int row = gw; row < ROWS; row += nw) {
        float d = dv2[row];
        float vin = in[(size_t)row * CC + lane];
        if (transform) vin = fmaxf(d * vin, 0.f);
        float acc = bl[lane];
#pragma unroll
        for (int kk = 0; kk < CC; ++kk) {
            float xv = __shfl(vin, kk);
            acc = fmaf(xv, Wl[kk * CC + lane], acc);
        }
        outP[(size_t)row * CC + lane] = 0.1f * d * acc;
    }
}

// ---------------------------------------------------------------------------
// Kernel 6: fused hyperedge gather + scatter.
// z[e,c] = sum_t P[v_t, c];  Acc[v_t, c] += z[e,c]  for all 10 members.
// One wave per edge (lane = channel).
// ---------------------------------------------------------------------------
__global__ void __launch_bounds__(256) edge_kernel(const float* __restrict__ P,
                                                   const int* __restrict__ topk,
                                                   float* __restrict__ Acc) {
    int wid = threadIdx.x >> 6, lane = threadIdx.x & 63;
    int e = blockIdx.x * 4 + wid;
    if (e >= ROWS) return;
    int b = e / NN;
    const int* tk = topk + e * KK;
    int v[KK];
#pragma unroll
    for (int t = 0; t < KK; ++t) v[t] = tk[t];
    float z = 0.f;
#pragma unroll
    for (int t = 0; t < KK; ++t) z += P[((size_t)b * NN + v[t]) * CC + lane];
#pragma unroll
    for (int t = 0; t < KK; ++t) atomicAdd(&Acc[((size_t)b * NN + v[t]) * CC + lane], z);
}

// ---------------------------------------------------------------------------
// Kernel 7: final conv + relu + sum.
// h2[u,c] = relu(dv2[u]*Acc[u,c]);  y[b,n] = relu(sum_c h2flat[c*1600+n]*w2[c]+b2)
// h2flat[c*1600+n] == h2[c*25 + n/64, n%64].  y1[b] = sum_n y[b,n].
// 64 blocks: 8 chunks of 200 positions per batch; atomicAdd partial to out[b].
// ---------------------------------------------------------------------------
__global__ void final_kernel(const float* __restrict__ Acc, const float* __restrict__ dv2,
                             const float* __restrict__ w, const float* __restrict__ bsc,
                             float* __restrict__ out) {
    __shared__ float red[256];
    int blk = blockIdx.x;           // 0..63
    int b = blk >> 3, chunk = blk & 7;
    int tid = threadIdx.x;
    float local = 0.f;
    if (tid < 200) {
        int n = chunk * 200 + tid;
        int q = n >> 6, r = n & 63;
        float acc = bsc[0];
#pragma unroll 8
        for (int c = 0; c < CC; ++c) {
            int rowl = c * 25 + q;
            float v = Acc[((size_t)b * NN + rowl) * CC + r];
            float h = fmaxf(dv2[b * NN + rowl] * v, 0.f);
            acc = fmaf(h, w[c], acc);
        }
        local = fmaxf(acc, 0.f);
    }
    red[tid] = local; __syncthreads();
    for (int s = 128; s > 0; s >>= 1) { if (tid < s) red[tid] += red[tid + s]; __syncthreads(); }
    if (tid == 0) atomicAdd(&out[b], red[0]);
}

// ---------------------------------------------------------------------------
extern "C" void kernel_launch(void* const* d_in, const int* in_sizes, int n_in,
                              void* d_out, int out_size, void* d_ws, size_t ws_size,
                              hipStream_t stream) {
    const float* x      = (const float*)d_in[0];
    const float* w_con1 = (const float*)d_in[1];
    const float* b_con1 = (const float*)d_in[2];
    const float* W1     = (const float*)d_in[3];
    const float* b1     = (const float*)d_in[4];
    const float* W2     = (const float*)d_in[5];
    const float* b2     = (const float*)d_in[6];
    const float* w_con2 = (const float*)d_in[7];
    const float* b_con2 = (const float*)d_in[8];
    // d_in[9] = k (always 10 here), d_in[10] = batch (unused)

    char* ws = (char*)d_ws;
    float* xx   = (float*)(ws + 0);        //  51200 B
    float* dv2  = (float*)(ws + 51200);    //  51200 B
    int*   DV   = (int*)  (ws + 102400);   //  51200 B
    float* pre  = (float*)(ws + 153600);   //  51200 B
    int*   topk = (int*)  (ws + 204800);   // 512000 B
    float* P    = (float*)(ws + 716800);   // 3276800 B
    float* Acc  = (float*)(ws + 3993600);  // 3276800 B  (total 7270400 B)

    float* out = (float*)d_out;

    conv_relu_kernel<<<(ROWS + 255) / 256, 256, 0, stream>>>(x, w_con1, b_con1, pre);
    softmax_kernel<<<BB, 256, 0, stream>>>(pre, xx);

    hipMemsetAsync(DV, 0, ROWS * sizeof(int), stream);
    topk_kernel<<<ROWS / 4, 256, 0, stream>>>(xx, topk, DV);
    dv2_kernel<<<(ROWS + 255) / 256, 256, 0, stream>>>(DV, dv2);

    // Layer 1: P = 0.1*dv2*(new@W1+b1); Acc = H (H^T P)
    lin_kernel<<<400, 256, 0, stream>>>(x, W1, b1, dv2, P, 0);
    hipMemsetAsync(Acc, 0, (size_t)ROWS * CC * sizeof(float), stream);
    edge_kernel<<<ROWS / 4, 256, 0, stream>>>(P, topk, Acc);

    // Layer 2: in = relu(dv2*Acc); P = 0.1*dv2*(in@W2+b2); Acc = H (H^T P)
    lin_kernel<<<400, 256, 0, stream>>>(Acc, W2, b2, dv2, P, 1);
    hipMemsetAsync(Acc, 0, (size_t)ROWS * CC * sizeof(float), stream);
    edge_kernel<<<ROWS / 4, 256, 0, stream>>>(P, topk, Acc);

    // Final conv + relu + per-batch sum
    hipMemsetAsync(out, 0, BB * sizeof(float), stream);
    final_kernel<<<64, 256, 0, stream>>>(Acc, dv2, w_con2, b_con2, out);
}